// Round 1
// baseline (121.228 us; speedup 1.0000x reference)
//
#include <hip/hip_runtime.h>

#define N_ANCH 268800
#define NCLS   80
#define MAXDET 300
#define CAP    512   // candidate cap / sort size (expected ~305 candidates)

__device__ __forceinline__ unsigned f2u(float f) { return __float_as_uint(f); }

// ---------------- K0: zero scratch region ----------------
__global__ void init_kernel(unsigned* __restrict__ p, int n) {
    int i = blockIdx.x * blockDim.x + threadIdx.x;
    if (i < n) p[i] = 0u;
}

// ---------------- K1: per-anchor max/argmax + coarse histogram ----------------
__global__ __launch_bounds__(256) void map_kernel(const float* __restrict__ pred,
                                                  unsigned* __restrict__ sbits,
                                                  int* __restrict__ cls,
                                                  unsigned* __restrict__ hist1) {
    __shared__ unsigned lh[16384];
    const int t = threadIdx.x;
    for (int k = t; k < 16384; k += 256) lh[k] = 0u;
    __syncthreads();

    const int i0 = (blockIdx.x * 256 + t) * 4;
    if (i0 < N_ANCH) {
        const float* base = pred + 4 * N_ANCH + i0;
        float4 best = *(const float4*)base;
        int4 bi = make_int4(0, 0, 0, 0);
#pragma unroll 4
        for (int c = 1; c < NCLS; ++c) {
            float4 v = *(const float4*)(base + (size_t)c * N_ANCH);
            if (v.x > best.x) { best.x = v.x; bi.x = c; }
            if (v.y > best.y) { best.y = v.y; bi.y = c; }
            if (v.z > best.z) { best.z = v.z; bi.z = c; }
            if (v.w > best.w) { best.w = v.w; bi.w = c; }
        }
        uint4 ub = make_uint4(f2u(best.x), f2u(best.y), f2u(best.z), f2u(best.w));
        *(uint4*)(sbits + i0) = ub;
        *(int4*)(cls + i0) = bi;
        atomicAdd(&lh[ub.x >> 16], 1u);
        atomicAdd(&lh[ub.y >> 16], 1u);
        atomicAdd(&lh[ub.z >> 16], 1u);
        atomicAdd(&lh[ub.w >> 16], 1u);
    }
    __syncthreads();
    for (int k = t; k < 16384; k += 256) {
        unsigned v = lh[k];
        if (v) atomicAdd(&hist1[k], v);
    }
}

// ---------------- K2: find coarse bin b1 (suffix count crossing 300) ----------------
__global__ __launch_bounds__(1024) void scan1_kernel(const unsigned* __restrict__ hist1,
                                                     unsigned* __restrict__ scal) {
    __shared__ unsigned c[1024];
    const int t = threadIdx.x;
    unsigned s = 0;
#pragma unroll
    for (int k = 0; k < 16; ++k) s += hist1[t * 16 + k];
    c[t] = s;
    __syncthreads();
    for (int ofs = 1; ofs < 1024; ofs <<= 1) {
        unsigned v = (t + ofs < 1024) ? c[t + ofs] : 0u;
        __syncthreads();
        c[t] += v;
        __syncthreads();
    }
    unsigned here = c[t];
    unsigned next = (t < 1023) ? c[t + 1] : 0u;
    if (here >= MAXDET && next < MAXDET) {
        unsigned running = next;
        for (int b = 15; b >= 0; --b) {
            unsigned nb = running + hist1[t * 16 + b];
            if (nb >= MAXDET) {
                scal[0] = (unsigned)(t * 16 + b); // b1
                scal[1] = running;                // count of bits with (bits>>16) > b1  (< 300)
                break;
            }
            running = nb;
        }
    }
}

// ---------------- K3: sub-histogram inside bin b1 ----------------
__global__ __launch_bounds__(256) void hist2_kernel(const unsigned* __restrict__ sbits,
                                                    const unsigned* __restrict__ scal,
                                                    unsigned* __restrict__ hist2) {
    const unsigned b1 = scal[0];
    for (int i = blockIdx.x * 256 + threadIdx.x; i < N_ANCH; i += 256 * 256) {
        unsigned bits = sbits[i];
        if ((bits >> 16) == b1) atomicAdd(&hist2[bits & 0xFFFFu], 1u);
    }
}

// ---------------- K4: exact bit threshold T ----------------
__global__ __launch_bounds__(1024) void scan2_kernel(const unsigned* __restrict__ hist2,
                                                     unsigned* __restrict__ scal) {
    __shared__ unsigned c[1024];
    const int t = threadIdx.x;
    const unsigned b1 = scal[0];
    const unsigned above = scal[1];
    const unsigned TH = MAXDET - above; // >= 1
    unsigned s = 0;
    for (int k = 0; k < 64; ++k) s += hist2[t * 64 + k];
    c[t] = s;
    __syncthreads();
    for (int ofs = 1; ofs < 1024; ofs <<= 1) {
        unsigned v = (t + ofs < 1024) ? c[t + ofs] : 0u;
        __syncthreads();
        c[t] += v;
        __syncthreads();
    }
    unsigned here = c[t];
    unsigned next = (t < 1023) ? c[t + 1] : 0u;
    if (here >= TH && next < TH) {
        unsigned running = next;
        for (int b = 63; b >= 0; --b) {
            unsigned nb = running + hist2[t * 64 + b];
            if (nb >= TH) {
                scal[2] = (b1 << 16) | (unsigned)(t * 64 + b); // T
                break;
            }
            running = nb;
        }
    }
}

// ---------------- K5: compact candidates >= T ----------------
__global__ __launch_bounds__(256) void compact_kernel(const unsigned* __restrict__ sbits,
                                                      unsigned* __restrict__ scal,
                                                      unsigned long long* __restrict__ cand) {
    const unsigned T = scal[2];
    for (int i = blockIdx.x * 256 + threadIdx.x; i < N_ANCH; i += 256 * 256) {
        unsigned bits = sbits[i];
        if (bits >= T) {
            unsigned pos = atomicAdd(&scal[3], 1u);
            if (pos < CAP)
                cand[pos] = ((unsigned long long)bits << 32) |
                            (unsigned long long)(0xFFFFFFFFu - (unsigned)i);
        }
    }
}

// ---------------- K6: sort + NMS + output ----------------
__global__ __launch_bounds__(512) void final_kernel(const float* __restrict__ pred,
                                                    const int* __restrict__ cls,
                                                    const unsigned* __restrict__ scal,
                                                    const unsigned long long* __restrict__ cand,
                                                    const int* __restrict__ orig_h,
                                                    const int* __restrict__ orig_w,
                                                    float* __restrict__ out) {
    __shared__ unsigned long long keys[CAP];
    __shared__ float bx1[MAXDET], by1[MAXDET], bx2[MAXDET], by2[MAXDET];
    __shared__ float barea[MAXDET], bscore[MAXDET], bcls[MAXDET];
    __shared__ unsigned sup[MAXDET * 10];
    __shared__ unsigned keepW[10];
    __shared__ __align__(16) float obuf[MAXDET * 6];

    const int t = threadIdx.x;
    const unsigned C = min(scal[3], (unsigned)CAP);

    keys[t] = (t < (int)C) ? cand[t] : 0ULL;
    for (int k = t; k < MAXDET * 10; k += 512) sup[k] = 0u;
    if (t < 10) keepW[t] = 0u;
    __syncthreads();

    // bitonic sort ascending over CAP=512 keys; element r-th largest at [511 - r]
    for (unsigned k = 2; k <= CAP; k <<= 1) {
        for (unsigned j = k >> 1; j > 0; j >>= 1) {
            unsigned i = (unsigned)t;
            unsigned ixj = i ^ j;
            if (ixj > i) {
                bool up = ((i & k) == 0);
                unsigned long long a = keys[i], b = keys[ixj];
                if ((a > b) == up) { keys[i] = b; keys[ixj] = a; }
            }
            __syncthreads();
        }
    }

    const float w_img = (float)orig_w[0];
    const float h_img = (float)orig_h[0];

    if (t < MAXDET) {
        float sc = 0.f, cx = 0.f, cy = 0.f, bw = 0.f, bh = 0.f, cf = 0.f;
        if (t < (int)C) {
            unsigned long long key = keys[CAP - 1 - t];
            unsigned bits = (unsigned)(key >> 32);
            unsigned idx = 0xFFFFFFFFu - (unsigned)(key & 0xFFFFFFFFull);
            sc = __uint_as_float(bits);
            cx = pred[0 * N_ANCH + idx];
            cy = pred[1 * N_ANCH + idx];
            bw = pred[2 * N_ANCH + idx];
            bh = pred[3 * N_ANCH + idx];
            cf = (float)cls[idx];
        }
        float x1 = cx - bw * 0.5f, y1 = cy - bh * 0.5f;
        float x2 = cx + bw * 0.5f, y2 = cy + bh * 0.5f;
        bx1[t] = x1; by1[t] = y1; bx2[t] = x2; by2[t] = y2;
        barea[t] = (x2 - x1) * (y2 - y1);
        bscore[t] = sc; bcls[t] = cf;
        if (sc > 0.5f) atomicOr(&keepW[t >> 5], 1u << (t & 31));
    }
    __syncthreads();

    // suppression matrix: bit j set in row i when i<j and IoU > 0.4
    for (int p = t; p < MAXDET * MAXDET; p += 512) {
        int i = p / MAXDET;
        int j = p - i * MAXDET;
        if (j > i) {
            float xx1 = fmaxf(bx1[i], bx1[j]);
            float yy1 = fmaxf(by1[i], by1[j]);
            float xx2 = fminf(bx2[i], bx2[j]);
            float yy2 = fminf(by2[i], by2[j]);
            float iw = fmaxf(xx2 - xx1, 0.f);
            float ih = fmaxf(yy2 - yy1, 0.f);
            float inter = iw * ih;
            float uni = barea[i] + barea[j] - inter;
            float iou = inter / (uni + 1e-9f);
            if (iou > 0.4f) atomicOr(&sup[i * 10 + (j >> 5)], 1u << (j & 31));
        }
    }
    __syncthreads();

    // serial greedy NMS on one wave: lanes 0..9 own 32-bit keep words
    if (t < 64) {
        unsigned kw = (t < 10) ? keepW[t] : 0u;
        for (int i = 0; i < MAXDET; ++i) {
            unsigned ow = __shfl(kw, i >> 5, 64);
            bool alive = (ow >> (i & 31)) & 1u;
            unsigned srow = (t < 10) ? sup[i * 10 + t] : 0u;
            if (alive) kw &= ~srow;
        }
        if (t < 10) keepW[t] = kw;
    }
    __syncthreads();

    if (t < MAXDET) {
        bool kp = (keepW[t >> 5] >> (t & 31)) & 1u;
        float o0 = fminf(fmaxf(bx1[t], 0.f), w_img);
        float o1 = fminf(fmaxf(by1[t], 0.f), h_img);
        float o2 = fminf(fmaxf(bx2[t], 0.f), w_img);
        float o3 = fminf(fmaxf(by2[t], 0.f), h_img);
        float o4 = bscore[t], o5 = bcls[t];
        if (!kp) { o0 = o1 = o2 = o3 = o4 = o5 = 0.f; }
        obuf[t * 6 + 0] = o0; obuf[t * 6 + 1] = o1; obuf[t * 6 + 2] = o2;
        obuf[t * 6 + 3] = o3; obuf[t * 6 + 4] = o4; obuf[t * 6 + 5] = o5;
    }
    __syncthreads();
    for (int v = t; v < (MAXDET * 6) / 4; v += 512)
        ((float4*)out)[v] = ((const float4*)obuf)[v];
}

extern "C" void kernel_launch(void* const* d_in, const int* in_sizes, int n_in,
                              void* d_out, int out_size, void* d_ws, size_t ws_size,
                              hipStream_t stream) {
    const float* pred = (const float*)d_in[0];
    const int* orig_h = (const int*)d_in[1];
    const int* orig_w = (const int*)d_in[2];
    float* out = (float*)d_out;

    char* w = (char*)d_ws;
    unsigned* sbits = (unsigned*)w;                              // N u32
    int* cls = (int*)(w + 1075200);                              // N i32
    unsigned* hist1 = (unsigned*)(w + 2150400);                  // 16384 u32
    unsigned* hist2 = (unsigned*)(w + 2215936);                  // 65536 u32
    unsigned* scal = (unsigned*)(w + 2478080);                   // 64 u32 (b1, above, T, count)
    unsigned long long* cand = (unsigned long long*)(w + 2478336); // CAP u64

    // zero hist1+hist2+scal+cand (contiguous: 332032 bytes = 83008 u32)
    init_kernel<<<(83008 + 255) / 256, 256, 0, stream>>>((unsigned*)(w + 2150400), 83008);
    map_kernel<<<(N_ANCH / 4 + 255) / 256, 256, 0, stream>>>(pred, sbits, cls, hist1);
    scan1_kernel<<<1, 1024, 0, stream>>>(hist1, scal);
    hist2_kernel<<<256, 256, 0, stream>>>(sbits, scal, hist2);
    scan2_kernel<<<1, 1024, 0, stream>>>(hist2, scal);
    compact_kernel<<<256, 256, 0, stream>>>(sbits, scal, cand);
    final_kernel<<<1, 512, 0, stream>>>(pred, cls, scal, cand, orig_h, orig_w, out);
}

// Round 2
// 85.481 us; speedup vs baseline: 1.4182x; 1.4182x over previous
//
#include <hip/hip_runtime.h>

#define N_ANCH 268800
#define NCLS   80
#define MAXDET 300
#define CAP    512   // candidate cap / sort size (expected ~305 candidates)
#define NW     10    // 32-bit words covering 300 rows

__device__ __forceinline__ unsigned f2u(float f) { return __float_as_uint(f); }

// ---------------- K0: zero scratch region ----------------
__global__ void init_kernel(unsigned* __restrict__ p, int n) {
    int i = blockIdx.x * blockDim.x + threadIdx.x;
    if (i < n) p[i] = 0u;
}

// ---------------- K1: per-anchor max/argmax + coarse histogram ----------------
__global__ __launch_bounds__(256) void map_kernel(const float* __restrict__ pred,
                                                  unsigned* __restrict__ sbits,
                                                  int* __restrict__ cls,
                                                  unsigned* __restrict__ hist1) {
    __shared__ unsigned lh[16384];
    const int t = threadIdx.x;
    for (int k = t; k < 16384; k += 256) lh[k] = 0u;
    __syncthreads();

    const int i0 = (blockIdx.x * 256 + t) * 4;
    if (i0 < N_ANCH) {
        const float* base = pred + 4 * N_ANCH + i0;
        float4 best = *(const float4*)base;
        int4 bi = make_int4(0, 0, 0, 0);
#pragma unroll 4
        for (int c = 1; c < NCLS; ++c) {
            float4 v = *(const float4*)(base + (size_t)c * N_ANCH);
            if (v.x > best.x) { best.x = v.x; bi.x = c; }
            if (v.y > best.y) { best.y = v.y; bi.y = c; }
            if (v.z > best.z) { best.z = v.z; bi.z = c; }
            if (v.w > best.w) { best.w = v.w; bi.w = c; }
        }
        uint4 ub = make_uint4(f2u(best.x), f2u(best.y), f2u(best.z), f2u(best.w));
        *(uint4*)(sbits + i0) = ub;
        *(int4*)(cls + i0) = bi;
        atomicAdd(&lh[ub.x >> 16], 1u);
        atomicAdd(&lh[ub.y >> 16], 1u);
        atomicAdd(&lh[ub.z >> 16], 1u);
        atomicAdd(&lh[ub.w >> 16], 1u);
    }
    __syncthreads();
    for (int k = t; k < 16384; k += 256) {
        unsigned v = lh[k];
        if (v) atomicAdd(&hist1[k], v);
    }
}

// ---------------- K2: find coarse bin b1 (suffix count crossing 300) ----------------
__global__ __launch_bounds__(1024) void scan1_kernel(const unsigned* __restrict__ hist1,
                                                     unsigned* __restrict__ scal) {
    __shared__ unsigned c[1024];
    const int t = threadIdx.x;
    unsigned s = 0;
#pragma unroll
    for (int k = 0; k < 16; ++k) s += hist1[t * 16 + k];
    c[t] = s;
    __syncthreads();
    for (int ofs = 1; ofs < 1024; ofs <<= 1) {
        unsigned v = (t + ofs < 1024) ? c[t + ofs] : 0u;
        __syncthreads();
        c[t] += v;
        __syncthreads();
    }
    unsigned here = c[t];
    unsigned next = (t < 1023) ? c[t + 1] : 0u;
    if (here >= MAXDET && next < MAXDET) {
        unsigned running = next;
        for (int b = 15; b >= 0; --b) {
            unsigned nb = running + hist1[t * 16 + b];
            if (nb >= MAXDET) {
                scal[0] = (unsigned)(t * 16 + b); // b1
                scal[1] = running;                // count of bits with (bits>>16) > b1  (< 300)
                break;
            }
            running = nb;
        }
    }
}

// ---------------- K3: sub-histogram inside bin b1 ----------------
__global__ __launch_bounds__(256) void hist2_kernel(const unsigned* __restrict__ sbits,
                                                    const unsigned* __restrict__ scal,
                                                    unsigned* __restrict__ hist2) {
    const unsigned b1 = scal[0];
    for (int i = blockIdx.x * 256 + threadIdx.x; i < N_ANCH; i += 256 * 256) {
        unsigned bits = sbits[i];
        if ((bits >> 16) == b1) atomicAdd(&hist2[bits & 0xFFFFu], 1u);
    }
}

// ---------------- K4: exact bit threshold T ----------------
__global__ __launch_bounds__(1024) void scan2_kernel(const unsigned* __restrict__ hist2,
                                                     unsigned* __restrict__ scal) {
    __shared__ unsigned c[1024];
    const int t = threadIdx.x;
    const unsigned b1 = scal[0];
    const unsigned above = scal[1];
    const unsigned TH = MAXDET - above; // >= 1
    unsigned s = 0;
    for (int k = 0; k < 64; ++k) s += hist2[t * 64 + k];
    c[t] = s;
    __syncthreads();
    for (int ofs = 1; ofs < 1024; ofs <<= 1) {
        unsigned v = (t + ofs < 1024) ? c[t + ofs] : 0u;
        __syncthreads();
        c[t] += v;
        __syncthreads();
    }
    unsigned here = c[t];
    unsigned next = (t < 1023) ? c[t + 1] : 0u;
    if (here >= TH && next < TH) {
        unsigned running = next;
        for (int b = 63; b >= 0; --b) {
            unsigned nb = running + hist2[t * 64 + b];
            if (nb >= TH) {
                scal[2] = (b1 << 16) | (unsigned)(t * 64 + b); // T
                break;
            }
            running = nb;
        }
    }
}

// ---------------- K5: compact candidates >= T ----------------
__global__ __launch_bounds__(256) void compact_kernel(const unsigned* __restrict__ sbits,
                                                      unsigned* __restrict__ scal,
                                                      unsigned long long* __restrict__ cand) {
    const unsigned T = scal[2];
    for (int i = blockIdx.x * 256 + threadIdx.x; i < N_ANCH; i += 256 * 256) {
        unsigned bits = sbits[i];
        if (bits >= T) {
            unsigned pos = atomicAdd(&scal[3], 1u);
            if (pos < CAP)
                cand[pos] = ((unsigned long long)bits << 32) |
                            (unsigned long long)(0xFFFFFFFFu - (unsigned)i);
        }
    }
}

// ---------------- K6a: bitonic sort + gather boxes ----------------
// boxes layout: [MAXDET][8] = x1,y1,x2,y2,area,score,cls,pad
__global__ __launch_bounds__(512) void sort_kernel(const float* __restrict__ pred,
                                                   const int* __restrict__ cls,
                                                   const unsigned* __restrict__ scal,
                                                   const unsigned long long* __restrict__ cand,
                                                   float* __restrict__ boxes) {
    __shared__ unsigned long long keys[CAP];
    const int t = threadIdx.x;
    const unsigned C = min(scal[3], (unsigned)CAP);

    keys[t] = (t < (int)C) ? cand[t] : 0ULL;
    __syncthreads();

    for (unsigned k = 2; k <= CAP; k <<= 1) {
        for (unsigned j = k >> 1; j > 0; j >>= 1) {
            unsigned i = (unsigned)t;
            unsigned ixj = i ^ j;
            if (ixj > i) {
                bool up = ((i & k) == 0);
                unsigned long long a = keys[i], b = keys[ixj];
                if ((a > b) == up) { keys[i] = b; keys[ixj] = a; }
            }
            __syncthreads();
        }
    }

    if (t < MAXDET) {
        float sc = 0.f, cx = 0.f, cy = 0.f, bw = 0.f, bh = 0.f, cf = 0.f;
        if (t < (int)C) {
            unsigned long long key = keys[CAP - 1 - t];
            unsigned bits = (unsigned)(key >> 32);
            unsigned idx = 0xFFFFFFFFu - (unsigned)(key & 0xFFFFFFFFull);
            sc = __uint_as_float(bits);
            cx = pred[0 * N_ANCH + idx];
            cy = pred[1 * N_ANCH + idx];
            bw = pred[2 * N_ANCH + idx];
            bh = pred[3 * N_ANCH + idx];
            cf = (float)cls[idx];
        }
        float x1 = cx - bw * 0.5f, y1 = cy - bh * 0.5f;
        float x2 = cx + bw * 0.5f, y2 = cy + bh * 0.5f;
        boxes[t * 8 + 0] = x1;
        boxes[t * 8 + 1] = y1;
        boxes[t * 8 + 2] = x2;
        boxes[t * 8 + 3] = y2;
        boxes[t * 8 + 4] = (x2 - x1) * (y2 - y1);
        boxes[t * 8 + 5] = sc;
        boxes[t * 8 + 6] = cf;
        boxes[t * 8 + 7] = 0.f;
    }
}

// ---------------- K6b: suppression matrix, one thread per (row, word) ----------------
__global__ __launch_bounds__(256) void iou_kernel(const float* __restrict__ boxes,
                                                  unsigned* __restrict__ sup) {
    __shared__ float bx1[MAXDET], by1[MAXDET], bx2[MAXDET], by2[MAXDET], ba[MAXDET];
    const int t = threadIdx.x;
    for (int i = t; i < MAXDET; i += 256) {
        bx1[i] = boxes[i * 8 + 0];
        by1[i] = boxes[i * 8 + 1];
        bx2[i] = boxes[i * 8 + 2];
        by2[i] = boxes[i * 8 + 3];
        ba[i]  = boxes[i * 8 + 4];
    }
    __syncthreads();

    const int gid = blockIdx.x * 256 + t; // word index: row i = gid/NW, word w = gid%NW
    if (gid < MAXDET * NW) {
        const int i = gid / NW;
        const int w = gid - i * NW;
        const float x1 = bx1[i], y1 = by1[i], x2 = bx2[i], y2 = by2[i], ar = ba[i];
        unsigned m = 0;
#pragma unroll
        for (int b = 0; b < 32; ++b) {
            const int j = w * 32 + b;
            if (j > i && j < MAXDET) {
                float xx1 = fmaxf(x1, bx1[j]);
                float yy1 = fmaxf(y1, by1[j]);
                float xx2 = fminf(x2, bx2[j]);
                float yy2 = fminf(y2, by2[j]);
                float iw = fmaxf(xx2 - xx1, 0.f);
                float ih = fmaxf(yy2 - yy1, 0.f);
                float inter = iw * ih;
                float uni = ar + ba[j] - inter;
                if (inter / (uni + 1e-9f) > 0.4f) m |= (1u << b);
            }
        }
        sup[gid] = m;
    }
}

// ---------------- K6c: serial greedy NMS (sparse) + output ----------------
__global__ __launch_bounds__(512) void nms_kernel(const float* __restrict__ boxes,
                                                  const unsigned* __restrict__ sup,
                                                  const int* __restrict__ orig_h,
                                                  const int* __restrict__ orig_w,
                                                  float* __restrict__ out) {
    __shared__ unsigned supL[MAXDET * NW];
    __shared__ unsigned keepW[NW], rowAny[NW];
    __shared__ __align__(16) float obuf[MAXDET * 6];

    const int t = threadIdx.x;
    if (t < NW) { keepW[t] = 0u; rowAny[t] = 0u; }
    for (int k = t; k < MAXDET * NW; k += 512) supL[k] = sup[k];
    __syncthreads();

    if (t < MAXDET) {
        if (boxes[t * 8 + 5] > 0.5f) atomicOr(&keepW[t >> 5], 1u << (t & 31));
        unsigned nz = 0;
#pragma unroll
        for (int w = 0; w < NW; ++w) nz |= supL[t * NW + w];
        if (nz) atomicOr(&rowAny[t >> 5], 1u << (t & 31));
    }
    __syncthreads();

    // serial greedy on wave 0; lanes 0..9 own keep words.
    // Only rows that are alive AND have a nonzero suppression row do work.
    if (t < 64) {
        const int lane = t;
        unsigned kw = (lane < NW) ? keepW[lane] : 0u;
        const unsigned ra = (lane < NW) ? rowAny[lane] : 0u;
#pragma unroll 1
        for (int w = 0; w < NW; ++w) {
            unsigned done = 0u;
            while (true) {
                unsigned aw = __shfl(kw, w, 64);
                unsigned rw = __shfl(ra, w, 64);
                unsigned m = aw & rw & ~done;
                if (m == 0u) break;
                int b = __ffs(m) - 1;
                done |= (1u << b);
                int i = w * 32 + b;
                unsigned srow = (lane < NW) ? supL[i * NW + lane] : 0u;
                kw &= ~srow;
            }
        }
        if (lane < NW) keepW[lane] = kw;
    }
    __syncthreads();

    const float w_img = (float)orig_w[0];
    const float h_img = (float)orig_h[0];

    if (t < MAXDET) {
        bool kp = (keepW[t >> 5] >> (t & 31)) & 1u;
        float x1 = boxes[t * 8 + 0], y1 = boxes[t * 8 + 1];
        float x2 = boxes[t * 8 + 2], y2 = boxes[t * 8 + 3];
        float o0 = fminf(fmaxf(x1, 0.f), w_img);
        float o1 = fminf(fmaxf(y1, 0.f), h_img);
        float o2 = fminf(fmaxf(x2, 0.f), w_img);
        float o3 = fminf(fmaxf(y2, 0.f), h_img);
        float o4 = boxes[t * 8 + 5], o5 = boxes[t * 8 + 6];
        if (!kp) { o0 = o1 = o2 = o3 = o4 = o5 = 0.f; }
        obuf[t * 6 + 0] = o0; obuf[t * 6 + 1] = o1; obuf[t * 6 + 2] = o2;
        obuf[t * 6 + 3] = o3; obuf[t * 6 + 4] = o4; obuf[t * 6 + 5] = o5;
    }
    __syncthreads();
    for (int v = t; v < (MAXDET * 6) / 4; v += 512)
        ((float4*)out)[v] = ((const float4*)obuf)[v];
}

extern "C" void kernel_launch(void* const* d_in, const int* in_sizes, int n_in,
                              void* d_out, int out_size, void* d_ws, size_t ws_size,
                              hipStream_t stream) {
    const float* pred = (const float*)d_in[0];
    const int* orig_h = (const int*)d_in[1];
    const int* orig_w = (const int*)d_in[2];
    float* out = (float*)d_out;

    char* w = (char*)d_ws;
    unsigned* sbits = (unsigned*)w;                                // N u32
    int* cls = (int*)(w + 1075200);                                // N i32
    unsigned* hist1 = (unsigned*)(w + 2150400);                    // 16384 u32
    unsigned* hist2 = (unsigned*)(w + 2215936);                    // 65536 u32
    unsigned* scal = (unsigned*)(w + 2478080);                     // 64 u32 (b1, above, T, count)
    unsigned long long* cand = (unsigned long long*)(w + 2478336); // CAP u64
    float* boxes = (float*)(w + 2482432);                          // 300*8 f32
    unsigned* sup = (unsigned*)(w + 2492032);                      // 3000 u32

    // zero hist1+hist2+scal (contiguous: 81984 u32)
    init_kernel<<<(81984 + 255) / 256, 256, 0, stream>>>(hist1, 81984);
    map_kernel<<<(N_ANCH / 4 + 255) / 256, 256, 0, stream>>>(pred, sbits, cls, hist1);
    scan1_kernel<<<1, 1024, 0, stream>>>(hist1, scal);
    hist2_kernel<<<256, 256, 0, stream>>>(sbits, scal, hist2);
    scan2_kernel<<<1, 1024, 0, stream>>>(hist2, scal);
    compact_kernel<<<256, 256, 0, stream>>>(sbits, scal, cand);
    sort_kernel<<<1, 512, 0, stream>>>(pred, cls, scal, cand, boxes);
    iou_kernel<<<(MAXDET * NW + 255) / 256, 256, 0, stream>>>(boxes, sup);
    nms_kernel<<<1, 512, 0, stream>>>(boxes, sup, orig_h, orig_w, out);
}